// Round 6
// baseline (368.900 us; speedup 1.0000x reference)
//
#include <hip/hip_runtime.h>
#include <hip/hip_bf16.h>
#include <math.h>

// ---------------------------------------------------------------------------
// PMLP_GCN forward:  3x (GEMM -> GCN-agg[+bias]) with BN+ReLU between,
// log_softmax at the end.  N=50000 E=640000 IN=500 HID=128 OUT=64, f32.
// R5: R4's depth-2 prefetch, but with NAMED per-depth register sets captured
//     directly by lambdas (no array-by-reference params -> no scratch; R4's
//     108MB/dispatch WRITE_SIZE was spill traffic). launch_bounds (256,3).
// ---------------------------------------------------------------------------

#define EPS_BN 1e-5f

typedef __attribute__((ext_vector_type(8))) _Float16 f16x8;
typedef __attribute__((ext_vector_type(4))) _Float16 f16x4;
typedef __attribute__((ext_vector_type(2))) _Float16 f16x2;
typedef __attribute__((ext_vector_type(4))) float    f32x4;

// ---------------- graph prep ----------------

__global__ void count_k(const int* __restrict__ src, const int* __restrict__ dst,
                        int* __restrict__ cnt, int E) {
    int e = blockIdx.x * 256 + threadIdx.x;
    if (e >= E) return;
    int s = src[e], d = dst[e];
    if (s != d) atomicAdd(&cnt[d], 1);
}

__global__ void prep_k(const int* __restrict__ cnt, float* __restrict__ dinv,
                       float* __restrict__ invdeg, int n) {
    int i = blockIdx.x * 256 + threadIdx.x;
    if (i >= n) return;
    float deg = (float)cnt[i] + 1.0f;   // +1 for added self loop
    dinv[i]   = rsqrtf(deg);
    invdeg[i] = 1.0f / deg;
}

// 3-kernel exclusive prefix scan over cnt[n] -> row_start
__global__ void scan1_k(const int* __restrict__ cnt, int* __restrict__ within,
                        int* __restrict__ btot, int n) {
    __shared__ int s[512];
    int tid = threadIdx.x;
    int i = blockIdx.x * 512 + tid;
    int val = (i < n) ? cnt[i] : 0;
    s[tid] = val;
    __syncthreads();
    for (int off = 1; off < 512; off <<= 1) {
        int v = (tid >= off) ? s[tid - off] : 0;
        __syncthreads();
        s[tid] += v;
        __syncthreads();
    }
    if (i < n) within[i] = s[tid] - val;   // exclusive
    if (tid == 511) btot[blockIdx.x] = s[511];
}

__global__ void scan2_k(const int* __restrict__ btot, int* __restrict__ boff, int nblk) {
    if (threadIdx.x == 0) {
        int run = 0;
        for (int b = 0; b < nblk; ++b) { boff[b] = run; run += btot[b]; }
    }
}

__global__ void scan3_k(const int* __restrict__ within, const int* __restrict__ boff,
                        int* __restrict__ row_start, int* __restrict__ cursor, int n) {
    int i = blockIdx.x * 256 + threadIdx.x;
    if (i >= n) return;
    int v = within[i] + boff[i >> 9];
    row_start[i] = v;
    cursor[i]    = v;
}

__global__ void fill_k(const int* __restrict__ src, const int* __restrict__ dst,
                       const float* __restrict__ dinv, int* __restrict__ cursor,
                       int* __restrict__ eidx, float* __restrict__ ew, int E) {
    int e = blockIdx.x * 256 + threadIdx.x;
    if (e >= E) return;
    int s = src[e], d = dst[e];
    if (s == d) return;
    int pos = atomicAdd(&cursor[d], 1);
    eidx[pos] = s;
    ew[pos]   = dinv[s] * dinv[d];
}

// ---- W f32 -> f16 with K padded to Kp (pad zero-filled) ----

__global__ void wcvt_k(const float* __restrict__ W, _Float16* __restrict__ Wh,
                       int rows, int K, int Kp) {
    int q = Kp >> 2;
    int idx = blockIdx.x * 256 + threadIdx.x;
    if (idx >= rows * q) return;
    int r = idx / q, k4 = (idx - r * q) * 4;
    f16x4 h = {(_Float16)0.f, (_Float16)0.f, (_Float16)0.f, (_Float16)0.f};
    if (k4 < K) {                        // K%4==0 -> all-or-none
        float4 v = *(const float4*)(W + (size_t)r * K + k4);
        h[0] = (_Float16)v.x; h[1] = (_Float16)v.y;
        h[2] = (_Float16)v.z; h[3] = (_Float16)v.w;
    }
    *(f16x4*)(Wh + (size_t)r * Kp + k4) = h;
}

// ---------------- MFMA GEMM: C[M,NC] = A[M,K] * Wh[NC,Kp]^T ----------------
// A f32 or f16 (converted in staging); W pre-converted f16 (Kp padded).
// f32 accumulate, f16 out. Block: 256 thr = 4 waves; tile 64 x NC; chunk 64.
// Depth-2 register prefetch with NAMED per-depth reg sets (awA.. / awB..)
// referenced directly from capturing lambdas -- arrays never passed as
// parameters, so SROA keeps them in VGPRs (R4 regression: array-by-ref
// lambda params took addresses -> scratch -> 95MB/dispatch spill traffic).
// LDS double-buffered, one barrier per chunk.
// LDS rows 128 B, XOR-swizzled (byte ^= (row&7)<<4): ds_read_b128 2-way max.

template <int NC, bool A_IS_F32>
__global__ __launch_bounds__(256, 3) void mgemm_k(const void* __restrict__ Av,
                                                  const _Float16* __restrict__ Wh,
                                                  _Float16* __restrict__ C,
                                                  int M, int K, int Kp) {
    constexpr int CT = NC / 16;            // col frags per wave
    constexpr int WI = NC / 32;            // W uint4 loads per thread
    __shared__ __align__(16) _Float16 As0[64 * 64];
    __shared__ __align__(16) _Float16 Ws0[NC * 64];
    __shared__ __align__(16) _Float16 As1[64 * 64];
    __shared__ __align__(16) _Float16 Ws1[NC * 64];

    const int tid  = threadIdx.x;
    const int lane = tid & 63, wave = tid >> 6;
    const int lrow = lane & 15, kg = lane >> 4;
    const int row0 = blockIdx.x * 64;

    f32x4 acc[CT] = {};

    // depth-A register set
    float4 awA0, awA1, awA2, awA3;        // A f32 path
    uint4  ahA0, ahA1;                    // A f16 path
    uint4  whA[WI];
    // depth-B register set
    float4 awB0, awB1, awB2, awB3;
    uint4  ahB0, ahB1;
    uint4  whB[WI];

    const float*    Af = (const float*)Av;
    const _Float16* Ah = (const _Float16*)Av;

    auto lda_f32 = [&](int c0, int it) -> float4 {
        int idx = tid + it * 256;
        int row = idx >> 4, slot = idx & 15;          // 16 float4/row
        int gr = row0 + row, gk = c0 * 64 + slot * 4;
        float4 v = make_float4(0.f, 0.f, 0.f, 0.f);
        if (gr < M && gk < K)                          // K%4==0
            v = *(const float4*)(Af + (size_t)gr * K + gk);
        return v;
    };
    auto lda_f16 = [&](int c0, int it) -> uint4 {
        int idx = tid + it * 256;
        int row = idx >> 3, slot = idx & 7;            // 8x 16B/row
        int gr = row0 + row, gk = c0 * 64 + slot * 8;
        uint4 v = make_uint4(0u, 0u, 0u, 0u);
        if (gr < M && gk < K)
            v = *(const uint4*)(Ah + (size_t)gr * K + gk);
        return v;
    };

    auto load_A = [&](int c0) {
        if constexpr (A_IS_F32) {
            awA0 = lda_f32(c0, 0); awA1 = lda_f32(c0, 1);
            awA2 = lda_f32(c0, 2); awA3 = lda_f32(c0, 3);
        } else {
            ahA0 = lda_f16(c0, 0); ahA1 = lda_f16(c0, 1);
        }
        #pragma unroll
        for (int it = 0; it < WI; ++it) {
            int idx = tid + it * 256;
            int row = idx >> 3, slot = idx & 7;
            whA[it] = *(const uint4*)(Wh + (size_t)row * Kp + c0 * 64 + slot * 8);
        }
    };
    auto load_B = [&](int c0) {
        if constexpr (A_IS_F32) {
            awB0 = lda_f32(c0, 0); awB1 = lda_f32(c0, 1);
            awB2 = lda_f32(c0, 2); awB3 = lda_f32(c0, 3);
        } else {
            ahB0 = lda_f16(c0, 0); ahB1 = lda_f16(c0, 1);
        }
        #pragma unroll
        for (int it = 0; it < WI; ++it) {
            int idx = tid + it * 256;
            int row = idx >> 3, slot = idx & 7;
            whB[it] = *(const uint4*)(Wh + (size_t)row * Kp + c0 * 64 + slot * 8);
        }
    };

    auto sta_f32 = [&](char* AsB, int it, float4 v) {
        int idx = tid + it * 256;
        int row = idx >> 4, slot = idx & 15;
        f16x4 h;
        h[0] = (_Float16)v.x; h[1] = (_Float16)v.y;
        h[2] = (_Float16)v.z; h[3] = (_Float16)v.w;
        int cb = (slot * 8) ^ ((row & 7) << 4);
        *(f16x4*)(AsB + row * 128 + cb) = h;
    };
    auto sta_f16 = [&](char* AsB, int it, uint4 v) {
        int idx = tid + it * 256;
        int row = idx >> 3, slot = idx & 7;
        int cb = (slot * 16) ^ ((row & 7) << 4);
        *(uint4*)(AsB + row * 128 + cb) = v;
    };

    auto store_A = [&](char* AsB, char* WsB) {
        if constexpr (A_IS_F32) {
            sta_f32(AsB, 0, awA0); sta_f32(AsB, 1, awA1);
            sta_f32(AsB, 2, awA2); sta_f32(AsB, 3, awA3);
        } else {
            sta_f16(AsB, 0, ahA0); sta_f16(AsB, 1, ahA1);
        }
        #pragma unroll
        for (int it = 0; it < WI; ++it) {
            int idx = tid + it * 256;
            int row = idx >> 3, slot = idx & 7;
            int cb = (slot * 16) ^ ((row & 7) << 4);
            *(uint4*)(WsB + row * 128 + cb) = whA[it];
        }
    };
    auto store_B = [&](char* AsB, char* WsB) {
        if constexpr (A_IS_F32) {
            sta_f32(AsB, 0, awB0); sta_f32(AsB, 1, awB1);
            sta_f32(AsB, 2, awB2); sta_f32(AsB, 3, awB3);
        } else {
            sta_f16(AsB, 0, ahB0); sta_f16(AsB, 1, ahB1);
        }
        #pragma unroll
        for (int it = 0; it < WI; ++it) {
            int idx = tid + it * 256;
            int row = idx >> 3, slot = idx & 7;
            int cb = (slot * 16) ^ ((row & 7) << 4);
            *(uint4*)(WsB + row * 128 + cb) = whB[it];
        }
    };

    auto compute = [&](const char* AsB, const char* WsB) {
        #pragma unroll
        for (int ks = 0; ks < 2; ++ks) {
            const int cbase = ks * 64 + kg * 16;
            f16x8 af, bf[CT];
            {
                int row = wave * 16 + lrow;
                af = *(const f16x8*)(AsB + row * 128 + (cbase ^ ((row & 7) << 4)));
            }
            #pragma unroll
            for (int ct = 0; ct < CT; ++ct) {
                int row = ct * 16 + lrow;
                bf[ct] = *(const f16x8*)(WsB + row * 128 + (cbase ^ ((row & 7) << 4)));
            }
            #pragma unroll
            for (int ct = 0; ct < CT; ++ct)
                acc[ct] = __builtin_amdgcn_mfma_f32_16x16x32_f16(
                    af, bf[ct], acc[ct], 0, 0, 0);
        }
    };

    const int nchunk = Kp >> 6;            // Kp % 64 == 0, nchunk >= 2
    // prologue: chunks 0,1 -> regs; chunk0 -> LDS0; chunk2 -> regs A
    load_A(0);
    load_B(1);
    store_A((char*)As0, (char*)Ws0);
    if (nchunk > 2) load_A(2);
    __syncthreads();

    int c = 0;
    while (true) {
        compute((const char*)As0, (const char*)Ws0);       // chunk c
        if (c + 1 >= nchunk) break;
        store_B((char*)As1, (char*)Ws1);                   // chunk c+1
        if (c + 3 < nchunk) load_B(c + 3);
        __syncthreads();

        compute((const char*)As1, (const char*)Ws1);       // chunk c+1
        if (c + 2 >= nchunk) break;
        store_A((char*)As0, (char*)Ws0);                   // chunk c+2
        if (c + 4 < nchunk) load_A(c + 4);
        __syncthreads();
        c += 2;
    }

    // ---- epilogue: D lane map col=lane&15, row=(lane>>4)*4+r ----
    #pragma unroll
    for (int r = 0; r < 4; ++r) {
        int grow = row0 + wave * 16 + kg * 4 + r;
        if (grow >= M) continue;
        #pragma unroll
        for (int ct = 0; ct < CT; ++ct)
            C[(size_t)grow * NC + ct * 16 + lrow] = (_Float16)acc[ct][r];
    }
}

// ---------------- GCN aggregation (gather over CSR, f16 rows) ----------------
// out[i] = sum_{e: dst=i} w_e * h[src_e] + invdeg[i]*h[i] + bias
// One wave per node, 4 nodes per 256-thread block, 4-edge unroll.

__global__ void agg128_k(const _Float16* __restrict__ h, const float* __restrict__ invdeg,
                         const int* __restrict__ row_start, const int* __restrict__ cnt,
                         const int* __restrict__ eidx, const float* __restrict__ ew,
                         const float* __restrict__ bias, float* __restrict__ out, int n) {
    const int wv = threadIdx.x >> 6, lane = threadIdx.x & 63;
    const int i = blockIdx.x * 4 + wv;
    if (i >= n) return;
    const int st = row_start[i], en = st + cnt[i];
    const float id = invdeg[i];
    const int c = lane * 2;

    f16x2 hv = *(const f16x2*)(h + (size_t)i * 128 + c);
    float a0 = fmaf(id, (float)hv[0], bias[c]);
    float a1 = fmaf(id, (float)hv[1], bias[c + 1]);
    int p = st;
    for (; p + 3 < en; p += 4) {
        int s0 = eidx[p], s1 = eidx[p + 1], s2 = eidx[p + 2], s3 = eidx[p + 3];
        float w0 = ew[p], w1 = ew[p + 1], w2 = ew[p + 2], w3 = ew[p + 3];
        f16x2 v0 = *(const f16x2*)(h + (size_t)s0 * 128 + c);
        f16x2 v1 = *(const f16x2*)(h + (size_t)s1 * 128 + c);
        f16x2 v2 = *(const f16x2*)(h + (size_t)s2 * 128 + c);
        f16x2 v3 = *(const f16x2*)(h + (size_t)s3 * 128 + c);
        a0 = fmaf(w0, (float)v0[0], a0); a1 = fmaf(w0, (float)v0[1], a1);
        a0 = fmaf(w1, (float)v1[0], a0); a1 = fmaf(w1, (float)v1[1], a1);
        a0 = fmaf(w2, (float)v2[0], a0); a1 = fmaf(w2, (float)v2[1], a1);
        a0 = fmaf(w3, (float)v3[0], a0); a1 = fmaf(w3, (float)v3[1], a1);
    }
    for (; p < en; ++p) {
        int s0 = eidx[p]; float w0 = ew[p];
        f16x2 v0 = *(const f16x2*)(h + (size_t)s0 * 128 + c);
        a0 = fmaf(w0, (float)v0[0], a0); a1 = fmaf(w0, (float)v0[1], a1);
    }
    out[(size_t)i * 128 + c]     = a0;
    out[(size_t)i * 128 + c + 1] = a1;
}

// ---- classifier agg (64 cols) with log_softmax fused (row == wave) ----

__global__ void aggsm_k(const _Float16* __restrict__ h, const float* __restrict__ invdeg,
                        const int* __restrict__ row_start, const int* __restrict__ cnt,
                        const int* __restrict__ eidx, const float* __restrict__ ew,
                        const float* __restrict__ bias, float* __restrict__ out, int n) {
    const int wv = threadIdx.x >> 6, lane = threadIdx.x & 63;
    const int i = blockIdx.x * 4 + wv;
    if (i >= n) return;
    const int st = row_start[i], en = st + cnt[i];
    const float id = invdeg[i];

    float a0 = fmaf(id, (float)h[(size_t)i * 64 + lane], bias[lane]);
    int p = st;
    for (; p + 3 < en; p += 4) {
        int s0 = eidx[p], s1 = eidx[p + 1], s2 = eidx[p + 2], s3 = eidx[p + 3];
        float w0 = ew[p], w1 = ew[p + 1], w2 = ew[p + 2], w3 = ew[p + 3];
        float v0 = (float)h[(size_t)s0 * 64 + lane];
        float v1 = (float)h[(size_t)s1 * 64 + lane];
        float v2 = (float)h[(size_t)s2 * 64 + lane];
        float v3 = (float)h[(size_t)s3 * 64 + lane];
        a0 = fmaf(w0, v0, a0); a0 = fmaf(w1, v1, a0);
        a0 = fmaf(w2, v2, a0); a0 = fmaf(w3, v3, a0);
    }
    for (; p < en; ++p)
        a0 = fmaf(ew[p], (float)h[(size_t)eidx[p] * 64 + lane], a0);

    // fused log_softmax over the 64-wide row held by this wave
    float m = a0;
    #pragma unroll
    for (int d = 32; d >= 1; d >>= 1) m = fmaxf(m, __shfl_xor(m, d, 64));
    float e = __expf(a0 - m);
    float s = e;
    #pragma unroll
    for (int d = 32; d >= 1; d >>= 1) s += __shfl_xor(s, d, 64);
    out[(size_t)i * 64 + lane] = a0 - m - __logf(s);
}

// ---------------- BatchNorm (affine=False) + ReLU ----------------

__global__ void stats_k(const float* __restrict__ a, float* __restrict__ gsum,
                        float* __restrict__ gsq, int n) {
    __shared__ float ls[256], lq[256];
    int tid = threadIdx.x;
    int c = tid & 127, g = tid >> 7;
    float s = 0.f, q = 0.f;
    for (int row = blockIdx.x * 2 + g; row < n; row += gridDim.x * 2) {
        float v = a[row * 128 + c];
        s += v; q += v * v;
    }
    ls[tid] = s; lq[tid] = q;
    __syncthreads();
    if (tid < 128) {
        atomicAdd(&gsum[c], ls[tid] + ls[tid + 128]);
        atomicAdd(&gsq[c],  lq[tid] + lq[tid + 128]);
    }
}

__global__ void finalize_k(const float* __restrict__ gsum, const float* __restrict__ gsq,
                           float* __restrict__ scale, float* __restrict__ shift, int n) {
    int c = threadIdx.x;   // 128
    float mean = gsum[c] / (float)n;
    float var  = gsq[c] / (float)n - mean * mean;
    float sc   = rsqrtf(var + EPS_BN);
    scale[c] = sc;
    shift[c] = -mean * sc;
}

// BN scale/shift + ReLU, f32 in -> f16 out (only consumer is the next GEMM)
__global__ void norm_k(const float* __restrict__ a, _Float16* __restrict__ o,
                       const float* __restrict__ scale, const float* __restrict__ shift,
                       int total4) {
    int idx = blockIdx.x * 256 + threadIdx.x;
    if (idx >= total4) return;
    float4 v = ((const float4*)a)[idx];
    int c0 = (idx & 31) * 4;
    f16x4 h;
    h[0] = (_Float16)fmaxf(0.f, fmaf(v.x, scale[c0 + 0], shift[c0 + 0]));
    h[1] = (_Float16)fmaxf(0.f, fmaf(v.y, scale[c0 + 1], shift[c0 + 1]));
    h[2] = (_Float16)fmaxf(0.f, fmaf(v.z, scale[c0 + 2], shift[c0 + 2]));
    h[3] = (_Float16)fmaxf(0.f, fmaf(v.w, scale[c0 + 3], shift[c0 + 3]));
    *(f16x4*)(o + (size_t)idx * 4) = h;
}

// ---------------------------------------------------------------------------

extern "C" void kernel_launch(void* const* d_in, const int* in_sizes, int n_in,
                              void* d_out, int out_size, void* d_ws, size_t ws_size,
                              hipStream_t stream) {
    const float* x  = (const float*)d_in[0];
    const int*   ei = (const int*)d_in[1];
    const float* W0 = (const float*)d_in[2];
    const float* b0 = (const float*)d_in[3];
    const float* W1 = (const float*)d_in[4];
    const float* b1 = (const float*)d_in[5];
    const float* W2 = (const float*)d_in[6];
    const float* b2 = (const float*)d_in[7];

    const int IN = 500;
    const int n = in_sizes[0] / IN;      // 50000
    const int E = in_sizes[1] / 2;       // 640000
    const int* src = ei;
    const int* dst = ei + E;

    // ---- workspace bump allocator (256B aligned) ----
    char* p = (char*)d_ws;
    auto alloc = [&](size_t bytes) -> void* {
        char* r = p;
        p += (bytes + 255) & ~(size_t)255;
        return (void*)r;
    };
    _Float16*  hb1h    = (_Float16*)alloc((size_t)n * 128 * 2); // GEMM out / agg in
    float*     hb2     = (float*)alloc((size_t)n * 128 * 4);    // agg out / BN in
    _Float16*  hb2h    = (_Float16*)alloc((size_t)n * 128 * 2); // BN out / GEMM in
    _Float16*  W0h     = (_Float16*)alloc((size_t)128 * 512 * 2);
    _Float16*  W1h     = (_Float16*)alloc((size_t)128 * 128 * 2);
    _Float16*  W2h     = (_Float16*)alloc((size_t)64 * 128 * 2);
    int*   deg_cnt  = (int*)alloc((size_t)n * 4);
    float* dinv     = (float*)alloc((size_t)n * 4);
    float* invdeg   = (float*)alloc((size_t)n * 4);
    int*   row_st   = (int*)alloc((size_t)n * 4);
    int*   cursor   = (int*)alloc((size_t)n * 4);
    int*   within   = (int*)alloc((size_t)n * 4);
    int*   btot     = (int*)alloc(256 * 4);
    int*   boff     = (int*)alloc(256 * 4);
    int*   eidx     = (int*)alloc((size_t)E * 4);
    float* ew       = (float*)alloc((size_t)E * 4);
    float* gsum     = (float*)alloc(128 * 4);   // gsum+gsq contiguous: one memset
    float* gsq      = (float*)alloc(128 * 4);
    float* scale    = (float*)alloc(128 * 4);
    float* shift    = (float*)alloc(128 * 4);
    (void)ws_size; (void)n_in; (void)out_size;

    float* out = (float*)d_out;

    const int gE = (E + 255) / 256;
    const int gN = (n + 255) / 256;
    const int nblk = (n + 511) / 512;
    const int gM = (n + 63) / 64;        // 782 blocks
    const int gA = (n + 3) / 4;          // 12500 blocks

    // ---- graph prep + weight conversion (once per call) ----
    hipMemsetAsync(deg_cnt, 0, (size_t)n * 4, stream);
    count_k<<<gE, 256, 0, stream>>>(src, dst, deg_cnt, E);
    prep_k<<<gN, 256, 0, stream>>>(deg_cnt, dinv, invdeg, n);
    scan1_k<<<nblk, 512, 0, stream>>>(deg_cnt, within, btot, n);
    scan2_k<<<1, 64, 0, stream>>>(btot, boff, nblk);
    scan3_k<<<gN, 256, 0, stream>>>(within, boff, row_st, cursor, n);
    fill_k<<<gE, 256, 0, stream>>>(src, dst, dinv, cursor, eidx, ew, E);
    wcvt_k<<<(128 * 512 / 4 + 255) / 256, 256, 0, stream>>>(W0, W0h, 128, 500, 512);
    wcvt_k<<<(128 * 128 / 4 + 255) / 256, 256, 0, stream>>>(W1, W1h, 128, 128, 128);
    wcvt_k<<<(64 * 128 / 4 + 255) / 256, 256, 0, stream>>>(W2, W2h, 64, 128, 128);

    // ---- layer 0 ----
    mgemm_k<128, true><<<gM, 256, 0, stream>>>(x, W0h, hb1h, n, 500, 512);
    agg128_k<<<gA, 256, 0, stream>>>(hb1h, invdeg, row_st, deg_cnt, eidx, ew, b0, hb2, n);
    hipMemsetAsync(gsum, 0, 256 * 4, stream);
    stats_k<<<256, 256, 0, stream>>>(hb2, gsum, gsq, n);
    finalize_k<<<1, 128, 0, stream>>>(gsum, gsq, scale, shift, n);
    norm_k<<<(n * 32 + 255) / 256, 256, 0, stream>>>(hb2, hb2h, scale, shift, n * 32);

    // ---- layer 1 ----
    mgemm_k<128, false><<<gM, 256, 0, stream>>>(hb2h, W1h, hb1h, n, 128, 128);
    agg128_k<<<gA, 256, 0, stream>>>(hb1h, invdeg, row_st, deg_cnt, eidx, ew, b1, hb2, n);
    hipMemsetAsync(gsum, 0, 256 * 4, stream);
    stats_k<<<256, 256, 0, stream>>>(hb2, gsum, gsq, n);
    finalize_k<<<1, 128, 0, stream>>>(gsum, gsq, scale, shift, n);
    norm_k<<<(n * 32 + 255) / 256, 256, 0, stream>>>(hb2, hb2h, scale, shift, n * 32);

    // ---- classifier (log_softmax fused into agg) ----
    mgemm_k<64, false><<<gM, 256, 0, stream>>>(hb2h, W2h, hb1h, n, 128, 128);
    aggsm_k<<<gA, 256, 0, stream>>>(hb1h, invdeg, row_st, deg_cnt, eidx, ew, b2, out, n);
}

// Round 7
// 343.822 us; speedup vs baseline: 1.0729x; 1.0729x over previous
//
#include <hip/hip_runtime.h>
#include <hip/hip_bf16.h>
#include <math.h>

// ---------------------------------------------------------------------------
// PMLP_GCN forward:  3x (GEMM -> GCN-agg[+bias]) with BN+ReLU between,
// log_softmax at the end.  N=50000 E=640000 IN=500 HID=128 OUT=64, f32.
// R6: GEMM staging via __builtin_amdgcn_global_load_lds (no prefetch VGPRs ->
//     no scratch spill, 1KB in flight per inst). Linear LDS dest + inverse-
//     swizzled global source + swizzled ds_read (both-sides rule). 2-phase
//     pipeline: stage(c+1) -> compute(c) -> vmcnt(0) -> s_barrier.
//     x pre-converted to f16 (padded K=512) once per call.
// ---------------------------------------------------------------------------

#define EPS_BN 1e-5f

typedef __attribute__((ext_vector_type(8))) _Float16 f16x8;
typedef __attribute__((ext_vector_type(4))) _Float16 f16x4;
typedef __attribute__((ext_vector_type(2))) _Float16 f16x2;
typedef __attribute__((ext_vector_type(4))) float    f32x4;

__device__ __forceinline__ void gload16(const void* g, void* l) {
    __builtin_amdgcn_global_load_lds(
        (const __attribute__((address_space(1))) void*)g,
        (__attribute__((address_space(3))) void*)l, 16, 0, 0);
}

// ---------------- graph prep ----------------

__global__ void count_k(const int* __restrict__ src, const int* __restrict__ dst,
                        int* __restrict__ cnt, int E) {
    int e = blockIdx.x * 256 + threadIdx.x;
    if (e >= E) return;
    int s = src[e], d = dst[e];
    if (s != d) atomicAdd(&cnt[d], 1);
}

__global__ void prep_k(const int* __restrict__ cnt, float* __restrict__ dinv,
                       float* __restrict__ invdeg, int n) {
    int i = blockIdx.x * 256 + threadIdx.x;
    if (i >= n) return;
    float deg = (float)cnt[i] + 1.0f;   // +1 for added self loop
    dinv[i]   = rsqrtf(deg);
    invdeg[i] = 1.0f / deg;
}

// 3-kernel exclusive prefix scan over cnt[n] -> row_start
__global__ void scan1_k(const int* __restrict__ cnt, int* __restrict__ within,
                        int* __restrict__ btot, int n) {
    __shared__ int s[512];
    int tid = threadIdx.x;
    int i = blockIdx.x * 512 + tid;
    int val = (i < n) ? cnt[i] : 0;
    s[tid] = val;
    __syncthreads();
    for (int off = 1; off < 512; off <<= 1) {
        int v = (tid >= off) ? s[tid - off] : 0;
        __syncthreads();
        s[tid] += v;
        __syncthreads();
    }
    if (i < n) within[i] = s[tid] - val;   // exclusive
    if (tid == 511) btot[blockIdx.x] = s[511];
}

__global__ void scan2_k(const int* __restrict__ btot, int* __restrict__ boff, int nblk) {
    if (threadIdx.x == 0) {
        int run = 0;
        for (int b = 0; b < nblk; ++b) { boff[b] = run; run += btot[b]; }
    }
}

__global__ void scan3_k(const int* __restrict__ within, const int* __restrict__ boff,
                        int* __restrict__ row_start, int* __restrict__ cursor, int n) {
    int i = blockIdx.x * 256 + threadIdx.x;
    if (i >= n) return;
    int v = within[i] + boff[i >> 9];
    row_start[i] = v;
    cursor[i]    = v;
}

__global__ void fill_k(const int* __restrict__ src, const int* __restrict__ dst,
                       const float* __restrict__ dinv, int* __restrict__ cursor,
                       int* __restrict__ eidx, float* __restrict__ ew, int E) {
    int e = blockIdx.x * 256 + threadIdx.x;
    if (e >= E) return;
    int s = src[e], d = dst[e];
    if (s == d) return;
    int pos = atomicAdd(&cursor[d], 1);
    eidx[pos] = s;
    ew[pos]   = dinv[s] * dinv[d];
}

// ---- f32 -> f16 with K padded to Kp (pad zero-filled); used for W and x ----

__global__ void wcvt_k(const float* __restrict__ W, _Float16* __restrict__ Wh,
                       int rows, int K, int Kp) {
    int q = Kp >> 2;
    long long idx = (long long)blockIdx.x * 256 + threadIdx.x;
    if (idx >= (long long)rows * q) return;
    int r = (int)(idx / q), k4 = (int)(idx - (long long)r * q) * 4;
    f16x4 h = {(_Float16)0.f, (_Float16)0.f, (_Float16)0.f, (_Float16)0.f};
    if (k4 < K) {                        // K%4==0 -> all-or-none
        float4 v = *(const float4*)(W + (size_t)r * K + k4);
        h[0] = (_Float16)v.x; h[1] = (_Float16)v.y;
        h[2] = (_Float16)v.z; h[3] = (_Float16)v.w;
    }
    *(f16x4*)(Wh + (size_t)r * Kp + k4) = h;
}

// ---------------- MFMA GEMM: C[M,NC] = A[M,Kp] * Wh[NC,Kp]^T ----------------
// A, Wh f16 (pre-converted, Kp padded with zeros). f32 accumulate, f16 out.
// Block: 256 thr = 4 waves; tile 64 x NC; chunk 64.
// Staging: global_load_lds (16B/lane, 1KB/inst, no VGPR round-trip).
// LDS image: row stride 128B, 16B-slot s of row holds global slot s^(row&7)
// (achieved by inverse-swizzling the per-lane GLOBAL address; LDS dest is
// linear wave-uniform base + lane*16). Fragment ds_read applies the same XOR
// -> 2-way max bank aliasing (free).
// Pipeline: stage(c+1); compute(c); s_waitcnt vmcnt(0); s_barrier.

template <int NC>
__global__ __launch_bounds__(256) void mgemm_k(const _Float16* __restrict__ A,
                                               const _Float16* __restrict__ Wh,
                                               _Float16* __restrict__ C,
                                               int M, int Kp) {
    constexpr int CT = NC / 16;            // col frags per wave
    constexpr int WJ = NC / 32;            // W gload insts per wave
    __shared__ __align__(16) _Float16 As[2][64 * 64];
    __shared__ __align__(16) _Float16 Ws[2][NC * 64];

    const int tid  = threadIdx.x;
    const int lane = tid & 63, wave = tid >> 6;
    const int lrow = lane & 15, kg = lane >> 4;
    const int row0 = blockIdx.x * 64;

    f32x4 acc[CT] = {};

    auto stage = [&](int c0, int b) {
        const int k0 = c0 * 64;
        // A tile: 64 rows x 128B -> 8 insts (2 per wave)
        #pragma unroll
        for (int j = 0; j < 2; ++j) {
            int li  = wave * 128 + j * 64 + lane;      // 0..511
            int row = li >> 3, s = li & 7;
            int gr  = row0 + row;
            int gs  = s ^ (row & 7);
            if (gr < M)
                gload16(A + (size_t)gr * Kp + k0 + gs * 8,
                        (char*)&As[b][0] + (wave * 128 + j * 64) * 16);
        }
        // W tile: NC rows x 128B -> NC/8 insts (WJ per wave)
        #pragma unroll
        for (int j = 0; j < WJ; ++j) {
            int li  = wave * (WJ * 64) + j * 64 + lane;
            int row = li >> 3, s = li & 7;
            int gs  = s ^ (row & 7);
            gload16(Wh + (size_t)row * Kp + k0 + gs * 8,
                    (char*)&Ws[b][0] + (wave * WJ + j) * 1024);
        }
    };

    auto compute = [&](int b) {
        const char* AsB = (const char*)&As[b][0];
        const char* WsB = (const char*)&Ws[b][0];
        #pragma unroll
        for (int ks = 0; ks < 2; ++ks) {
            const int cbase = ks * 64 + kg * 16;       // byte offset in row
            f16x8 af, bf[CT];
            {
                int row = wave * 16 + lrow;
                af = *(const f16x8*)(AsB + row * 128 + (cbase ^ ((row & 7) << 4)));
            }
            #pragma unroll
            for (int ct = 0; ct < CT; ++ct) {
                int row = ct * 16 + lrow;
                bf[ct] = *(const f16x8*)(WsB + row * 128 + (cbase ^ ((row & 7) << 4)));
            }
            #pragma unroll
            for (int ct = 0; ct < CT; ++ct)
                acc[ct] = __builtin_amdgcn_mfma_f32_16x16x32_f16(
                    af, bf[ct], acc[ct], 0, 0, 0);
        }
    };

    const int nchunk = Kp >> 6;            // Kp % 64 == 0
    stage(0, 0);
    asm volatile("s_waitcnt vmcnt(0)" ::: "memory");
    __builtin_amdgcn_s_barrier();
    __builtin_amdgcn_sched_barrier(0);

    for (int c = 0; c < nchunk; ++c) {
        const int b = c & 1;
        if (c + 1 < nchunk) stage(c + 1, b ^ 1);   // loads fly during compute
        compute(b);
        if (c + 1 < nchunk) {
            asm volatile("s_waitcnt vmcnt(0)" ::: "memory");
            __builtin_amdgcn_s_barrier();
            __builtin_amdgcn_sched_barrier(0);
        }
    }

    // ---- epilogue: D lane map col=lane&15, row=(lane>>4)*4+r ----
    #pragma unroll
    for (int r = 0; r < 4; ++r) {
        int grow = row0 + wave * 16 + kg * 4 + r;
        if (grow >= M) continue;
        #pragma unroll
        for (int ct = 0; ct < CT; ++ct)
            C[(size_t)grow * NC + ct * 16 + lrow] = (_Float16)acc[ct][r];
    }
}

// ---------------- GCN aggregation (gather over CSR, f16 rows) ----------------
// out[i] = sum_{e: dst=i} w_e * h[src_e] + invdeg[i]*h[i] + bias
// One wave per node, 4 nodes per 256-thread block, 4-edge unroll.

__global__ void agg128_k(const _Float16* __restrict__ h, const float* __restrict__ invdeg,
                         const int* __restrict__ row_start, const int* __restrict__ cnt,
                         const int* __restrict__ eidx, const float* __restrict__ ew,
                         const float* __restrict__ bias, float* __restrict__ out, int n) {
    const int wv = threadIdx.x >> 6, lane = threadIdx.x & 63;
    const int i = blockIdx.x * 4 + wv;
    if (i >= n) return;
    const int st = row_start[i], en = st + cnt[i];
    const float id = invdeg[i];
    const int c = lane * 2;

    f16x2 hv = *(const f16x2*)(h + (size_t)i * 128 + c);
    float a0 = fmaf(id, (float)hv[0], bias[c]);
    float a1 = fmaf(id, (float)hv[1], bias[c + 1]);
    int p = st;
    for (; p + 3 < en; p += 4) {
        int s0 = eidx[p], s1 = eidx[p + 1], s2 = eidx[p + 2], s3 = eidx[p + 3];
        float w0 = ew[p], w1 = ew[p + 1], w2 = ew[p + 2], w3 = ew[p + 3];
        f16x2 v0 = *(const f16x2*)(h + (size_t)s0 * 128 + c);
        f16x2 v1 = *(const f16x2*)(h + (size_t)s1 * 128 + c);
        f16x2 v2 = *(const f16x2*)(h + (size_t)s2 * 128 + c);
        f16x2 v3 = *(const f16x2*)(h + (size_t)s3 * 128 + c);
        a0 = fmaf(w0, (float)v0[0], a0); a1 = fmaf(w0, (float)v0[1], a1);
        a0 = fmaf(w1, (float)v1[0], a0); a1 = fmaf(w1, (float)v1[1], a1);
        a0 = fmaf(w2, (float)v2[0], a0); a1 = fmaf(w2, (float)v2[1], a1);
        a0 = fmaf(w3, (float)v3[0], a0); a1 = fmaf(w3, (float)v3[1], a1);
    }
    for (; p < en; ++p) {
        int s0 = eidx[p]; float w0 = ew[p];
        f16x2 v0 = *(const f16x2*)(h + (size_t)s0 * 128 + c);
        a0 = fmaf(w0, (float)v0[0], a0); a1 = fmaf(w0, (float)v0[1], a1);
    }
    out[(size_t)i * 128 + c]     = a0;
    out[(size_t)i * 128 + c + 1] = a1;
}

// ---- classifier agg (64 cols) with log_softmax fused (row == wave) ----

__global__ void aggsm_k(const _Float16* __restrict__ h, const float* __restrict__ invdeg,
                        const int* __restrict__ row_start, const int* __restrict__ cnt,
                        const int* __restrict__ eidx, const float* __restrict__ ew,
                        const float* __restrict__ bias, float* __restrict__ out, int n) {
    const int wv = threadIdx.x >> 6, lane = threadIdx.x & 63;
    const int i = blockIdx.x * 4 + wv;
    if (i >= n) return;
    const int st = row_start[i], en = st + cnt[i];
    const float id = invdeg[i];

    float a0 = fmaf(id, (float)h[(size_t)i * 64 + lane], bias[lane]);
    int p = st;
    for (; p + 3 < en; p += 4) {
        int s0 = eidx[p], s1 = eidx[p + 1], s2 = eidx[p + 2], s3 = eidx[p + 3];
        float w0 = ew[p], w1 = ew[p + 1], w2 = ew[p + 2], w3 = ew[p + 3];
        float v0 = (float)h[(size_t)s0 * 64 + lane];
        float v1 = (float)h[(size_t)s1 * 64 + lane];
        float v2 = (float)h[(size_t)s2 * 64 + lane];
        float v3 = (float)h[(size_t)s3 * 64 + lane];
        a0 = fmaf(w0, v0, a0); a0 = fmaf(w1, v1, a0);
        a0 = fmaf(w2, v2, a0); a0 = fmaf(w3, v3, a0);
    }
    for (; p < en; ++p)
        a0 = fmaf(ew[p], (float)h[(size_t)eidx[p] * 64 + lane], a0);

    // fused log_softmax over the 64-wide row held by this wave
    float m = a0;
    #pragma unroll
    for (int d = 32; d >= 1; d >>= 1) m = fmaxf(m, __shfl_xor(m, d, 64));
    float e = __expf(a0 - m);
    float s = e;
    #pragma unroll
    for (int d = 32; d >= 1; d >>= 1) s += __shfl_xor(s, d, 64);
    out[(size_t)i * 64 + lane] = a0 - m - __logf(s);
}

// ---------------- BatchNorm (affine=False) + ReLU ----------------

__global__ void stats_k(const float* __restrict__ a, float* __restrict__ gsum,
                        float* __restrict__ gsq, int n) {
    __shared__ float ls[256], lq[256];
    int tid = threadIdx.x;
    int c = tid & 127, g = tid >> 7;
    float s = 0.f, q = 0.f;
    for (int row = blockIdx.x * 2 + g; row < n; row += gridDim.x * 2) {
        float v = a[row * 128 + c];
        s += v; q += v * v;
    }
    ls[tid] = s; lq[tid] = q;
    __syncthreads();
    if (tid < 128) {
        atomicAdd(&gsum[c], ls[tid] + ls[tid + 128]);
        atomicAdd(&gsq[c],  lq[tid] + lq[tid + 128]);
    }
}

__global__ void finalize_k(const float* __restrict__ gsum, const float* __restrict__ gsq,
                           float* __restrict__ scale, float* __restrict__ shift, int n) {
    int c = threadIdx.x;   // 128
    float mean = gsum[c] / (float)n;
    float var  = gsq[c] / (float)n - mean * mean;
    float sc   = rsqrtf(var + EPS_BN);
    scale[c] = sc;
    shift[c] = -mean * sc;
}

// BN scale/shift + ReLU, f32 in -> f16 out (only consumer is the next GEMM)
__global__ void norm_k(const float* __restrict__ a, _Float16* __restrict__ o,
                       const float* __restrict__ scale, const float* __restrict__ shift,
                       int total4) {
    int idx = blockIdx.x * 256 + threadIdx.x;
    if (idx >= total4) return;
    float4 v = ((const float4*)a)[idx];
    int c0 = (idx & 31) * 4;
    f16x4 h;
    h[0] = (_Float16)fmaxf(0.f, fmaf(v.x, scale[c0 + 0], shift[c0 + 0]));
    h[1] = (_Float16)fmaxf(0.f, fmaf(v.y, scale[c0 + 1], shift[c0 + 1]));
    h[2] = (_Float16)fmaxf(0.f, fmaf(v.z, scale[c0 + 2], shift[c0 + 2]));
    h[3] = (_Float16)fmaxf(0.f, fmaf(v.w, scale[c0 + 3], shift[c0 + 3]));
    *(f16x4*)(o + (size_t)idx * 4) = h;
}

// ---------------------------------------------------------------------------

extern "C" void kernel_launch(void* const* d_in, const int* in_sizes, int n_in,
                              void* d_out, int out_size, void* d_ws, size_t ws_size,
                              hipStream_t stream) {
    const float* x  = (const float*)d_in[0];
    const int*   ei = (const int*)d_in[1];
    const float* W0 = (const float*)d_in[2];
    const float* b0 = (const float*)d_in[3];
    const float* W1 = (const float*)d_in[4];
    const float* b1 = (const float*)d_in[5];
    const float* W2 = (const float*)d_in[6];
    const float* b2 = (const float*)d_in[7];

    const int IN = 500;
    const int n = in_sizes[0] / IN;      // 50000
    const int E = in_sizes[1] / 2;       // 640000
    const int* src = ei;
    const int* dst = ei + E;

    // ---- workspace bump allocator (256B aligned) ----
    char* p = (char*)d_ws;
    auto alloc = [&](size_t bytes) -> void* {
        char* r = p;
        p += (bytes + 255) & ~(size_t)255;
        return (void*)r;
    };
    _Float16*  xh      = (_Float16*)alloc((size_t)n * 512 * 2);  // x as f16, K padded
    _Float16*  hb1h    = (_Float16*)alloc((size_t)n * 128 * 2);  // GEMM out / agg in
    float*     hb2     = (float*)alloc((size_t)n * 128 * 4);     // agg out / BN in
    _Float16*  hb2h    = (_Float16*)alloc((size_t)n * 128 * 2);  // BN out / GEMM in
    _Float16*  W0h     = (_Float16*)alloc((size_t)128 * 512 * 2);
    _Float16*  W1h     = (_Float16*)alloc((size_t)128 * 128 * 2);
    _Float16*  W2h     = (_Float16*)alloc((size_t)64 * 128 * 2);
    int*   deg_cnt  = (int*)alloc((size_t)n * 4);
    float* dinv     = (float*)alloc((size_t)n * 4);
    float* invdeg   = (float*)alloc((size_t)n * 4);
    int*   row_st   = (int*)alloc((size_t)n * 4);
    int*   cursor   = (int*)alloc((size_t)n * 4);
    int*   within   = (int*)alloc((size_t)n * 4);
    int*   btot     = (int*)alloc(256 * 4);
    int*   boff     = (int*)alloc(256 * 4);
    int*   eidx     = (int*)alloc((size_t)E * 4);
    float* ew       = (float*)alloc((size_t)E * 4);
    float* gsum     = (float*)alloc(128 * 4);   // gsum+gsq contiguous: one memset
    float* gsq      = (float*)alloc(128 * 4);
    float* scale    = (float*)alloc(128 * 4);
    float* shift    = (float*)alloc(128 * 4);
    (void)ws_size; (void)n_in; (void)out_size;

    float* out = (float*)d_out;

    const int gE = (E + 255) / 256;
    const int gN = (n + 255) / 256;
    const int nblk = (n + 511) / 512;
    const int gM = (n + 63) / 64;        // 782 blocks
    const int gA = (n + 3) / 4;          // 12500 blocks

    // ---- graph prep + f16 conversions (once per call) ----
    hipMemsetAsync(deg_cnt, 0, (size_t)n * 4, stream);
    count_k<<<gE, 256, 0, stream>>>(src, dst, deg_cnt, E);
    prep_k<<<gN, 256, 0, stream>>>(deg_cnt, dinv, invdeg, n);
    scan1_k<<<nblk, 512, 0, stream>>>(deg_cnt, within, btot, n);
    scan2_k<<<1, 64, 0, stream>>>(btot, boff, nblk);
    scan3_k<<<gN, 256, 0, stream>>>(within, boff, row_st, cursor, n);
    fill_k<<<gE, 256, 0, stream>>>(src, dst, dinv, cursor, eidx, ew, E);
    wcvt_k<<<(128 * 512 / 4 + 255) / 256, 256, 0, stream>>>(W0, W0h, 128, 500, 512);
    wcvt_k<<<(128 * 128 / 4 + 255) / 256, 256, 0, stream>>>(W1, W1h, 128, 128, 128);
    wcvt_k<<<(64 * 128 / 4 + 255) / 256, 256, 0, stream>>>(W2, W2h, 64, 128, 128);
    wcvt_k<<<(n * 128 + 255) / 256, 256, 0, stream>>>(x, xh, n, 500, 512);

    // ---- layer 0 ----
    mgemm_k<128><<<gM, 256, 0, stream>>>(xh, W0h, hb1h, n, 512);
    agg128_k<<<gA, 256, 0, stream>>>(hb1h, invdeg, row_st, deg_cnt, eidx, ew, b0, hb2, n);
    hipMemsetAsync(gsum, 0, 256 * 4, stream);
    stats_k<<<256, 256, 0, stream>>>(hb2, gsum, gsq, n);
    finalize_k<<<1, 128, 0, stream>>>(gsum, gsq, scale, shift, n);
    norm_k<<<(n * 32 + 255) / 256, 256, 0, stream>>>(hb2, hb2h, scale, shift, n * 32);

    // ---- layer 1 ----
    mgemm_k<128><<<gM, 256, 0, stream>>>(hb2h, W1h, hb1h, n, 128);
    agg128_k<<<gA, 256, 0, stream>>>(hb1h, invdeg, row_st, deg_cnt, eidx, ew, b1, hb2, n);
    hipMemsetAsync(gsum, 0, 256 * 4, stream);
    stats_k<<<256, 256, 0, stream>>>(hb2, gsum, gsq, n);
    finalize_k<<<1, 128, 0, stream>>>(gsum, gsq, scale, shift, n);
    norm_k<<<(n * 32 + 255) / 256, 256, 0, stream>>>(hb2, hb2h, scale, shift, n * 32);

    // ---- classifier (log_softmax fused into agg) ----
    mgemm_k<64><<<gM, 256, 0, stream>>>(hb2h, W2h, hb1h, n, 128);
    aggsm_k<<<gA, 256, 0, stream>>>(hb1h, invdeg, row_st, deg_cnt, eidx, ew, b2, out, n);
}